// Round 5
// baseline (209.973 us; speedup 1.0000x reference)
//
#include <hip/hip_runtime.h>

typedef _Float16 f16;
typedef _Float16 f16x4 __attribute__((ext_vector_type(4)));
typedef _Float16 f16x8 __attribute__((ext_vector_type(8)));
typedef float f32x4 __attribute__((ext_vector_type(4)));

// A layout in LDS: A[px][k], k = n*256+c, 16 px x 2048 f16 (4096 B per px row).
// 16-B chunks XOR-swizzled by (px & 7): byte = px*4096 + ((k>>3)^(px&7))*16 + (k&7)*2
// -> scatter stores spread banks; all 16-B frag reads are 2-way max (free).
static __device__ inline char* a_addr(char* Abase, int px, int k) {
    return Abase + px * 4096 + ((((k >> 3) ^ (px & 7)) << 4) | ((k & 7) << 1));
}

// ---------------------------------------------------------------------------
// k_setup: one launch, no internal deps.
// blocks 0..63:   (b,e): full query path redundantly: qe=emb[q[b]],
//                 x1=silu(qe@w1+b1), qh_e=x1@w2_e+b2_e, qk=w_kvK_e·qh_e, rw fold
// blocks 64..319: M_e = Wv_e @ w_out_e, rw-folded, f16 transposed
// ---------------------------------------------------------------------------
__launch_bounds__(256)
__global__ void k_setup(const int* __restrict__ q, const float* __restrict__ emb,
                        const float* __restrict__ w1, const float* __restrict__ b1,
                        const float* __restrict__ w2, const float* __restrict__ b2,
                        const float* __restrict__ w_kv, const float* __restrict__ w_out,
                        const float* __restrict__ rms_w,
                        f16* __restrict__ qkw, f16* __restrict__ mt) {
    int blk = blockIdx.x;
    int t = threadIdx.x;
    __shared__ float qe[256];
    __shared__ float x1L[512];
    __shared__ float ps[4][64];
    __shared__ float qhL[64];
    __shared__ float wv[64][8];

    if (blk < 64) {
        // ---- query-path role: (b, e) ----
        int b = blk >> 3, e = blk & 7;
        qe[t] = emb[(size_t)q[b] * 256 + t];
        __syncthreads();
        float a0 = b1[t], a1 = b1[t + 256];
        for (int c = 0; c < 256; ++c) {
            float qv = qe[c];
            a0 += qv * w1[c * 512 + t];
            a1 += qv * w1[c * 512 + t + 256];
        }
        x1L[t]       = a0 / (1.f + __expf(-a0));
        x1L[t + 256] = a1 / (1.f + __expf(-a1));
        __syncthreads();
        int d = t & 63, ks = t >> 6;
        float acc = 0.f;
        for (int k = ks * 128; k < ks * 128 + 128; ++k)
            acc += x1L[k] * w2[k * 512 + e * 64 + d];
        ps[ks][d] = acc;
        __syncthreads();
        if (t < 64)
            qhL[t] = b2[e * 64 + t] + ps[0][t] + ps[1][t] + ps[2][t] + ps[3][t];
        __syncthreads();
        const float* row = w_kv + (size_t)t * 1024 + e * 128;   // K-half of head e
        float a2 = 0.f;
#pragma unroll
        for (int dd = 0; dd < 64; dd += 4) {
            float4 wv4 = *(const float4*)(row + dd);
            a2 += qhL[dd] * wv4.x + qhL[dd + 1] * wv4.y + qhL[dd + 2] * wv4.z + qhL[dd + 3] * wv4.w;
        }
        qkw[(b * 8 + e) * 256 + t] = (f16)(a2 * rms_w[t]);
    } else {
        // ---- M role ----
        int mb = blk - 64;
        int e = mb >> 5, c0 = (mb & 31) * 8;
        {
            int d = t & 63, cc = t >> 6;   // cc 0..3, covers c 0..3 and 4..7
            wv[d][cc]     = w_kv[(size_t)(c0 + cc) * 1024 + e * 128 + 64 + d];
            wv[d][cc + 4] = w_kv[(size_t)(c0 + cc + 4) * 1024 + e * 128 + 64 + d];
        }
        __syncthreads();
        int o = t;
        float acc[8];
#pragma unroll
        for (int c = 0; c < 8; ++c) acc[c] = 0.f;
        for (int d = 0; d < 64; ++d) {
            float wo = w_out[(size_t)(e * 64 + d) * 256 + o];
            float4 wa = *(const float4*)&wv[d][0];
            float4 wb = *(const float4*)&wv[d][4];
            acc[0] += wa.x * wo; acc[1] += wa.y * wo; acc[2] += wa.z * wo; acc[3] += wa.w * wo;
            acc[4] += wb.x * wo; acc[5] += wb.y * wo; acc[6] += wb.z * wo; acc[7] += wb.w * wo;
        }
        f16x8 ov;
#pragma unroll
        for (int c = 0; c < 8; ++c) ov[c] = (f16)(acc[c] * rms_w[c0 + c]);
        *(f16x8*)(mt + (size_t)o * 2048 + e * 256 + c0) = ov;
    }
}

// ---------------------------------------------------------------------------
// k_attn: 512 threads, 16 pixels/block. load raw c + sumsq -> rinv; dots via
// MFMA (qk B-frag straight from global); softmax (rinv folded); blend in
// place; MFMA GEMM vs mt; store.  grid 512 (tile*8 + b). XOR-swizzled A.
// ---------------------------------------------------------------------------
__launch_bounds__(512, 4)
__global__ void k_attn(const float* __restrict__ cin, const f16* __restrict__ qkw,
                       const f16* __restrict__ mt, const float* __restrict__ b_out,
                       float* __restrict__ out) {
    int blk = blockIdx.x;
    int b = blk & 7;
    int hw0 = (blk >> 3) * 16;
    int t = threadIdx.x;
    int lane = t & 63, w = t >> 6;        // w 0..7
    int m16 = lane & 15, quad = lane >> 4;

    __shared__ char A[16 * 4096];         // 65536 B, swizzled f16 [16px][2048k]
    __shared__ float dotsP[16][8][8];     //  4096 B (later holds attn')
    __shared__ float wred[8][8][4][4];    //  4096 B
    __shared__ float rinvL[16][8];        //   512 B

    // ---- load raw c -> A (f16, swizzled), sum-of-squares via wave butterfly ----
    const float* cb = cin + ((size_t)b * 8 * 256) * 1024 + hw0;
    for (int g = 0; g < 8; ++g) {         // g = n
        f32x4 s = {0.f, 0.f, 0.f, 0.f};
#pragma unroll
        for (int i = 0; i < 2; ++i) {
            int idx = t + i * 512;        // 0..1023 = 256 ch x 4 pxg
            int ch = idx >> 2, pxg = idx & 3;
            float4 v = *(const float4*)(cb + ((size_t)(g * 256 + ch) << 10) + pxg * 4);
            int k = g * 256 + ch;
            *(f16*)a_addr(A, pxg * 4 + 0, k) = (f16)v.x;
            *(f16*)a_addr(A, pxg * 4 + 1, k) = (f16)v.y;
            *(f16*)a_addr(A, pxg * 4 + 2, k) = (f16)v.z;
            *(f16*)a_addr(A, pxg * 4 + 3, k) = (f16)v.w;
            s[0] += v.x * v.x; s[1] += v.y * v.y; s[2] += v.z * v.z; s[3] += v.w * v.w;
        }
#pragma unroll
        for (int m = 4; m <= 32; m <<= 1) {
            s[0] += __shfl_xor(s[0], m); s[1] += __shfl_xor(s[1], m);
            s[2] += __shfl_xor(s[2], m); s[3] += __shfl_xor(s[3], m);
        }
        if (lane < 4) *(f32x4*)&wred[w][g][lane][0] = s;   // lane==pxg
    }
    __syncthreads();

    // ---- rinv (t<128) + dots via MFMA (wave w -> n=w) ----
    if (t < 128) {
        int p = t >> 3, n = t & 7;
        float ss = 0.f;
#pragma unroll
        for (int ww = 0; ww < 8; ++ww) ss += wred[ww][n][p >> 2][p & 3];
        rinvL[p][n] = rsqrtf(ss * (1.f / 256.f) + 1e-6f);
    }
    {
        f32x4 d0 = {0.f, 0.f, 0.f, 0.f};
        const f16* qrow = qkw + (size_t)b * 2048 + (m16 & 7) * 256;
#pragma unroll
        for (int ks = 0; ks < 8; ++ks) {
            f16x8 a0  = *(const f16x8*)a_addr(A, m16, w * 256 + ks * 32 + quad * 8);
            f16x8 bfr = *(const f16x8*)(qrow + ks * 32 + quad * 8);
            d0 = __builtin_amdgcn_mfma_f32_16x16x32_f16(a0, bfr, d0, 0, 0, 0);
        }
        if (m16 < 8) {   // D: col=m16=e, row=quad*4+r=p
#pragma unroll
            for (int r = 0; r < 4; ++r) dotsP[quad * 4 + r][w][m16] = d0[r];
        }
    }
    __syncthreads();

    // ---- softmax with rinv fold (t<128): attn'[p][n][e] in place ----
    if (t < 128) {
        int p = t >> 3, e = t & 7;
        float l[8];
#pragma unroll
        for (int n = 0; n < 8; ++n) l[n] = dotsP[p][n][e] * rinvL[p][n] * 0.125f;
        float mx = l[0];
#pragma unroll
        for (int n = 1; n < 8; ++n) mx = fmaxf(mx, l[n]);
        float s = 0.f;
#pragma unroll
        for (int n = 0; n < 8; ++n) { l[n] = __expf(l[n] - mx); s += l[n]; }
        float inv = 1.f / s;
#pragma unroll
        for (int n = 0; n < 8; ++n) dotsP[p][n][e] = l[n] * inv * rinvL[p][n];
    }
    __syncthreads();

    // ---- blend: a[p][e][c] = sum_n attn'[p][n][e] * A[p][n][c], in place ----
    {
        int px = t & 15, c0 = (t >> 4) * 8;   // 16 px x 32 c-windows of 8
        float at[8][8];
#pragma unroll
        for (int e = 0; e < 8; ++e)
#pragma unroll
            for (int n = 0; n < 8; ++n) at[e][n] = dotsP[px][n][e];
#pragma unroll
        for (int cc = 0; cc < 8; cc += 4) {
            int c = c0 + cc;
            float cv[8][4];
#pragma unroll
            for (int n = 0; n < 8; ++n) {
                f16x4 hv = *(const f16x4*)a_addr(A, px, n * 256 + c);
                cv[n][0] = (float)hv[0]; cv[n][1] = (float)hv[1];
                cv[n][2] = (float)hv[2]; cv[n][3] = (float)hv[3];
            }
#pragma unroll
            for (int e = 0; e < 8; ++e) {
                float r0 = 0.f, r1 = 0.f, r2 = 0.f, r3 = 0.f;
#pragma unroll
                for (int n = 0; n < 8; ++n) {
                    float an = at[e][n];
                    r0 += an * cv[n][0]; r1 += an * cv[n][1];
                    r2 += an * cv[n][2]; r3 += an * cv[n][3];
                }
                f16x4 ov; ov[0] = (f16)r0; ov[1] = (f16)r1; ov[2] = (f16)r2; ov[3] = (f16)r3;
                *(f16x4*)a_addr(A, px, e * 256 + c) = ov;
            }
        }
    }
    __syncthreads();

    // ---- GEMM: out[16p][256o] = A[16][2048] @ mt^T  (wave w -> o 32-slice) ----
    {
        f32x4 acc[2];
        acc[0] = (f32x4){0.f, 0.f, 0.f, 0.f};
        acc[1] = (f32x4){0.f, 0.f, 0.f, 0.f};
#pragma unroll 8
        for (int ks = 0; ks < 64; ++ks) {
            int k = (ks >> 3) * 256 + (ks & 7) * 32 + quad * 8;
            f16x8 af = *(const f16x8*)a_addr(A, m16, k);
#pragma unroll
            for (int ot = 0; ot < 2; ++ot) {
                f16x8 bfr = *(const f16x8*)(mt + (size_t)(w * 32 + ot * 16 + m16) * 2048
                                            + ks * 32 + quad * 8);
                acc[ot] = __builtin_amdgcn_mfma_f32_16x16x32_f16(af, bfr, acc[ot], 0, 0, 0);
            }
        }
#pragma unroll
        for (int ot = 0; ot < 2; ++ot) {
            int o = w * 32 + ot * 16 + m16;
            float bo = b_out[o];
            float4 vv = {acc[ot][0] + bo, acc[ot][1] + bo, acc[ot][2] + bo, acc[ot][3] + bo};
            *(float4*)(out + ((size_t)b * 256 + o) * 1024 + hw0 + quad * 4) = vv;
        }
    }
}

extern "C" void kernel_launch(void* const* d_in, const int* in_sizes, int n_in,
                              void* d_out, int out_size, void* d_ws, size_t ws_size,
                              hipStream_t stream) {
    (void)in_sizes; (void)n_in; (void)out_size; (void)ws_size;
    const int*   q     = (const int*)d_in[0];
    const float* c     = (const float*)d_in[1];
    const float* rms_w = (const float*)d_in[2];
    const float* emb   = (const float*)d_in[3];
    const float* w1    = (const float*)d_in[4];
    const float* b1    = (const float*)d_in[5];
    const float* w2    = (const float*)d_in[6];
    const float* b2    = (const float*)d_in[7];
    const float* w_kv  = (const float*)d_in[8];
    const float* w_out = (const float*)d_in[9];
    const float* b_out = (const float*)d_in[10];
    float* out = (float*)d_out;

    // ws layout: qkw [8b][8e][256c] f16 = 32 KiB at 0; mt [256o][2048k] f16 = 1 MiB
    char* ws = (char*)d_ws;
    f16* qkw = (f16*)ws;                 // [0, 32768)
    f16* mt  = (f16*)(ws + 32768);       // [32768, +1 MiB)

    k_setup<<<320, 256, 0, stream>>>(q, emb, w1, b1, w2, b2, w_kv, w_out, rms_w, qkw, mt);
    k_attn <<<512, 512, 0, stream>>>(c, qkw, mt, b_out, out);
}

// Round 6
// 187.395 us; speedup vs baseline: 1.1205x; 1.1205x over previous
//
#include <hip/hip_runtime.h>

typedef _Float16 f16;
typedef _Float16 f16x4 __attribute__((ext_vector_type(4)));
typedef _Float16 f16x8 __attribute__((ext_vector_type(8)));
typedef float f32x4 __attribute__((ext_vector_type(4)));

// A layout in LDS: A[px][k], k = n*256+c, 16 px x 2048 f16 (4096 B per row).
// 16-B chunks XOR-swizzled by full 4-bit px: byte = px*4096 + ((k>>3)^px)*16 + (k&7)*2
// Stores are one f16x8 per (px, 8-ch) -> 16 lanes hit 16 distinct chunks (free);
// all frag reads (16-B and 8-B) are <=2-way (free).
static __device__ inline char* a_addr(char* Abase, int px, int k) {
    return Abase + px * 4096 + ((((k >> 3) ^ px) << 4) | ((k & 7) << 1));
}

// ---------------------------------------------------------------------------
// k_setup: one launch, no internal deps.
// blocks 0..63:   (b,e): full query path redundantly: qe=emb[q[b]],
//                 x1=silu(qe@w1+b1), qh_e=x1@w2_e+b2_e, qk=w_kvK_e·qh_e, rw fold
// blocks 64..319: M_e = Wv_e @ w_out_e, rw-folded, stored as
//                 mtp[kchunk][o][8] f16  (kchunk = (e*256+c0)/8)
// ---------------------------------------------------------------------------
__launch_bounds__(256)
__global__ void k_setup(const int* __restrict__ q, const float* __restrict__ emb,
                        const float* __restrict__ w1, const float* __restrict__ b1,
                        const float* __restrict__ w2, const float* __restrict__ b2,
                        const float* __restrict__ w_kv, const float* __restrict__ w_out,
                        const float* __restrict__ rms_w,
                        f16* __restrict__ qkw, f16* __restrict__ mtp) {
    int blk = blockIdx.x;
    int t = threadIdx.x;
    __shared__ float qe[256];
    __shared__ float x1L[512];
    __shared__ float ps[4][64];
    __shared__ float qhL[64];
    __shared__ float wv[64][8];

    if (blk < 64) {
        // ---- query-path role: (b, e) ----
        int b = blk >> 3, e = blk & 7;
        qe[t] = emb[(size_t)q[b] * 256 + t];
        __syncthreads();
        float a0 = b1[t], a1 = b1[t + 256];
        for (int c = 0; c < 256; ++c) {
            float qv = qe[c];
            a0 += qv * w1[c * 512 + t];
            a1 += qv * w1[c * 512 + t + 256];
        }
        x1L[t]       = a0 / (1.f + __expf(-a0));
        x1L[t + 256] = a1 / (1.f + __expf(-a1));
        __syncthreads();
        int d = t & 63, ks = t >> 6;
        float acc = 0.f;
        for (int k = ks * 128; k < ks * 128 + 128; ++k)
            acc += x1L[k] * w2[k * 512 + e * 64 + d];
        ps[ks][d] = acc;
        __syncthreads();
        if (t < 64)
            qhL[t] = b2[e * 64 + t] + ps[0][t] + ps[1][t] + ps[2][t] + ps[3][t];
        __syncthreads();
        const float* row = w_kv + (size_t)t * 1024 + e * 128;   // K-half of head e
        float a2 = 0.f;
#pragma unroll
        for (int dd = 0; dd < 64; dd += 4) {
            float4 wv4 = *(const float4*)(row + dd);
            a2 += qhL[dd] * wv4.x + qhL[dd + 1] * wv4.y + qhL[dd + 2] * wv4.z + qhL[dd + 3] * wv4.w;
        }
        qkw[(b * 8 + e) * 256 + t] = (f16)(a2 * rms_w[t]);
    } else {
        // ---- M role: (e, 8-c tile) ----
        int mb = blk - 64;
        int e = mb >> 5, c0 = (mb & 31) * 8;
        {
            int d = t & 63, cc = t >> 6;   // cc 0..3, covers c 0..3 and 4..7
            wv[d][cc]     = w_kv[(size_t)(c0 + cc) * 1024 + e * 128 + 64 + d];
            wv[d][cc + 4] = w_kv[(size_t)(c0 + cc + 4) * 1024 + e * 128 + 64 + d];
        }
        __syncthreads();
        int o = t;
        float acc[8];
#pragma unroll
        for (int c = 0; c < 8; ++c) acc[c] = 0.f;
        for (int d = 0; d < 64; ++d) {
            float wo = w_out[(size_t)(e * 64 + d) * 256 + o];
            float4 wa = *(const float4*)&wv[d][0];
            float4 wb = *(const float4*)&wv[d][4];
            acc[0] += wa.x * wo; acc[1] += wa.y * wo; acc[2] += wa.z * wo; acc[3] += wa.w * wo;
            acc[4] += wb.x * wo; acc[5] += wb.y * wo; acc[6] += wb.z * wo; acc[7] += wb.w * wo;
        }
        f16x8 ov;
#pragma unroll
        for (int c = 0; c < 8; ++c) ov[c] = (f16)(acc[c] * rms_w[c0 + c]);
        // mtp[kchunk][o][8], kchunk = (e*256+c0)>>3
        *(f16x8*)(mtp + ((size_t)((e * 256 + c0) >> 3) * 256 + o) * 8) = ov;
    }
}

// ---------------------------------------------------------------------------
// k_attn: 512 threads, 16 pixels/block. k-packed staged loads (1 ds_write_b128
// per thread per n), swizzled A; dots via MFMA; softmax (rinv folded); blend
// in place; MFMA GEMM vs mtp; store.  grid 512 (tile*8 + b).
// ---------------------------------------------------------------------------
__launch_bounds__(512, 4)
__global__ void k_attn(const float* __restrict__ cin, const f16* __restrict__ qkw,
                       const f16* __restrict__ mtp, const float* __restrict__ b_out,
                       float* __restrict__ out) {
    int blk = blockIdx.x;
    int b = blk & 7;
    int hw0 = (blk >> 3) * 16;
    int t = threadIdx.x;
    int lane = t & 63, w = t >> 6;        // w 0..7
    int m16 = lane & 15, quad = lane >> 4;

    __shared__ char A[16 * 4096];         // 65536 B, swizzled f16 [16px][2048k]
    __shared__ float dotsP[8][8][16];     //  4096 B [n][e][px] (later attn')
    __shared__ float wred[8][8][16];      //  4096 B [w][n][px]
    __shared__ float rinvL[16][8];        //   512 B

    // ---- load raw c -> A (f16, swizzled): thread = (px, 8-ch block) ----
    int px = t & 15, cb = t >> 4;         // cb 0..31
    const float* cbase = cin + ((size_t)b * 8 * 256) * 1024 + hw0 + px;
    for (int g = 0; g < 8; ++g) {         // g = n
        const float* src = cbase + ((size_t)(g * 256 + cb * 8) << 10);
        float v[8];
#pragma unroll
        for (int j = 0; j < 8; ++j) v[j] = src[(size_t)j << 10];
        float s = 0.f;
        f16x8 hv;
#pragma unroll
        for (int j = 0; j < 8; ++j) { s += v[j] * v[j]; hv[j] = (f16)v[j]; }
        *(f16x8*)a_addr(A, px, g * 256 + cb * 8) = hv;
        // reduce over the 4 cb's of this wave (lanes ^16, ^32)
        s += __shfl_xor(s, 16);
        s += __shfl_xor(s, 32);
        if (lane < 16) wred[w][g][px] = s;
    }
    __syncthreads();

    // ---- rinv (t<128) + dots via MFMA (wave w -> n=w) ----
    if (t < 128) {
        int p = t >> 3, n = t & 7;
        float ss = 0.f;
#pragma unroll
        for (int ww = 0; ww < 8; ++ww) ss += wred[ww][n][p];
        rinvL[p][n] = rsqrtf(ss * (1.f / 256.f) + 1e-6f);
    }
    {
        f32x4 d0 = {0.f, 0.f, 0.f, 0.f};
        const f16* qrow = qkw + (size_t)b * 2048 + (m16 & 7) * 256;
#pragma unroll
        for (int ks = 0; ks < 8; ++ks) {
            f16x8 a0  = *(const f16x8*)a_addr(A, m16, w * 256 + ks * 32 + quad * 8);
            f16x8 bfr = *(const f16x8*)(qrow + ks * 32 + quad * 8);
            d0 = __builtin_amdgcn_mfma_f32_16x16x32_f16(a0, bfr, d0, 0, 0, 0);
        }
        if (m16 < 8) {   // D: col=m16=e, row=quad*4+r=p
#pragma unroll
            for (int r = 0; r < 4; ++r) dotsP[w][m16][quad * 4 + r] = d0[r];
        }
    }
    __syncthreads();

    // ---- softmax with rinv fold (t<128): attn'[n][e][p] in place ----
    if (t < 128) {
        int p = t >> 3, e = t & 7;
        float l[8];
#pragma unroll
        for (int n = 0; n < 8; ++n) l[n] = dotsP[n][e][p] * rinvL[p][n] * 0.125f;
        float mx = l[0];
#pragma unroll
        for (int n = 1; n < 8; ++n) mx = fmaxf(mx, l[n]);
        float s = 0.f;
#pragma unroll
        for (int n = 0; n < 8; ++n) { l[n] = __expf(l[n] - mx); s += l[n]; }
        float inv = 1.f / s;
#pragma unroll
        for (int n = 0; n < 8; ++n) dotsP[n][e][p] = l[n] * inv * rinvL[p][n];
    }
    __syncthreads();

    // ---- blend: a[p][e][c] = sum_n attn'[n][e][p] * A[p][n][c], in place ----
    {
        int bpx = t & 15, c0 = (t >> 4) * 8;   // 16 px x 32 c-windows of 8
        float at[8][8];
#pragma unroll
        for (int e = 0; e < 8; ++e)
#pragma unroll
            for (int n = 0; n < 8; ++n) at[e][n] = dotsP[n][e][bpx];
#pragma unroll
        for (int cc = 0; cc < 8; cc += 4) {
            int c = c0 + cc;
            float cv[8][4];
#pragma unroll
            for (int n = 0; n < 8; ++n) {
                f16x4 hv = *(const f16x4*)a_addr(A, bpx, n * 256 + c);
                cv[n][0] = (float)hv[0]; cv[n][1] = (float)hv[1];
                cv[n][2] = (float)hv[2]; cv[n][3] = (float)hv[3];
            }
#pragma unroll
            for (int e = 0; e < 8; ++e) {
                float r0 = 0.f, r1 = 0.f, r2 = 0.f, r3 = 0.f;
#pragma unroll
                for (int n = 0; n < 8; ++n) {
                    float an = at[e][n];
                    r0 += an * cv[n][0]; r1 += an * cv[n][1];
                    r2 += an * cv[n][2]; r3 += an * cv[n][3];
                }
                f16x4 ov; ov[0] = (f16)r0; ov[1] = (f16)r1; ov[2] = (f16)r2; ov[3] = (f16)r3;
                *(f16x4*)a_addr(A, bpx, e * 256 + c) = ov;
            }
        }
    }
    __syncthreads();

    // ---- GEMM: out[16p][256o] = A[16][2048] @ M  (wave w -> o 32-slice) ----
    {
        f32x4 acc[2];
        acc[0] = (f32x4){0.f, 0.f, 0.f, 0.f};
        acc[1] = (f32x4){0.f, 0.f, 0.f, 0.f};
#pragma unroll 8
        for (int ks = 0; ks < 64; ++ks) {
            int k = (ks >> 3) * 256 + (ks & 7) * 32 + quad * 8;
            f16x8 af = *(const f16x8*)a_addr(A, m16, k);
            int kchunk = k >> 3;                       // = global k/8
#pragma unroll
            for (int ot = 0; ot < 2; ++ot) {
                f16x8 bfr = *(const f16x8*)(mtp + ((size_t)kchunk * 256
                                            + w * 32 + ot * 16 + m16) * 8);
                acc[ot] = __builtin_amdgcn_mfma_f32_16x16x32_f16(af, bfr, acc[ot], 0, 0, 0);
            }
        }
#pragma unroll
        for (int ot = 0; ot < 2; ++ot) {
            int o = w * 32 + ot * 16 + m16;
            float bo = b_out[o];
            float4 vv = {acc[ot][0] + bo, acc[ot][1] + bo, acc[ot][2] + bo, acc[ot][3] + bo};
            *(float4*)(out + ((size_t)b * 256 + o) * 1024 + hw0 + quad * 4) = vv;
        }
    }
}

extern "C" void kernel_launch(void* const* d_in, const int* in_sizes, int n_in,
                              void* d_out, int out_size, void* d_ws, size_t ws_size,
                              hipStream_t stream) {
    (void)in_sizes; (void)n_in; (void)out_size; (void)ws_size;
    const int*   q     = (const int*)d_in[0];
    const float* c     = (const float*)d_in[1];
    const float* rms_w = (const float*)d_in[2];
    const float* emb   = (const float*)d_in[3];
    const float* w1    = (const float*)d_in[4];
    const float* b1    = (const float*)d_in[5];
    const float* w2    = (const float*)d_in[6];
    const float* b2    = (const float*)d_in[7];
    const float* w_kv  = (const float*)d_in[8];
    const float* w_out = (const float*)d_in[9];
    const float* b_out = (const float*)d_in[10];
    float* out = (float*)d_out;

    // ws layout: qkw [8b][8e][256c] f16 = 32 KiB at 0; mtp [256kc][256o][8] f16 = 1 MiB
    char* ws = (char*)d_ws;
    f16* qkw = (f16*)ws;                 // [0, 32768)
    f16* mtp = (f16*)(ws + 32768);       // [32768, +1 MiB)

    k_setup<<<320, 256, 0, stream>>>(q, emb, w1, b1, w2, b2, w_kv, w_out, rms_w, qkw, mtp);
    k_attn <<<512, 512, 0, stream>>>(c, qkw, mtp, b_out, out);
}

// Round 7
// 173.329 us; speedup vs baseline: 1.2114x; 1.0812x over previous
//
#include <hip/hip_runtime.h>

typedef _Float16 f16;
typedef _Float16 f16x4 __attribute__((ext_vector_type(4)));
typedef _Float16 f16x8 __attribute__((ext_vector_type(8)));
typedef float f32x4 __attribute__((ext_vector_type(4)));

// A layout in LDS: A[px][k], k = n*256+c, 16 px x 2048 f16 (4096 B per row).
// 16-B chunks XOR-swizzled by full 4-bit px: byte = px*4096 + ((k>>3)^px)*16 + (k&7)*2
static __device__ inline char* a_addr(char* Abase, int px, int k) {
    return Abase + px * 4096 + ((((k >> 3) ^ px) << 4) | ((k & 7) << 1));
}

// ---------------------------------------------------------------------------
// k_setup: one launch, no internal deps.
// blocks 0..63:   (b,e): full query path redundantly
// blocks 64..319: M_e = Wv_e @ w_out_e, rw-folded -> mtp[kchunk][o][8] f16
// ---------------------------------------------------------------------------
__launch_bounds__(256)
__global__ void k_setup(const int* __restrict__ q, const float* __restrict__ emb,
                        const float* __restrict__ w1, const float* __restrict__ b1,
                        const float* __restrict__ w2, const float* __restrict__ b2,
                        const float* __restrict__ w_kv, const float* __restrict__ w_out,
                        const float* __restrict__ rms_w,
                        f16* __restrict__ qkw, f16* __restrict__ mtp) {
    int blk = blockIdx.x;
    int t = threadIdx.x;
    __shared__ float qe[256];
    __shared__ float x1L[512];
    __shared__ float ps[4][64];
    __shared__ float qhL[64];
    __shared__ float wv[64][8];

    if (blk < 64) {
        // ---- query-path role: (b, e) ----
        int b = blk >> 3, e = blk & 7;
        qe[t] = emb[(size_t)q[b] * 256 + t];
        __syncthreads();
        float a0 = b1[t], a1 = b1[t + 256];
#pragma unroll 4
        for (int c = 0; c < 256; ++c) {
            float qv = qe[c];
            a0 += qv * w1[c * 512 + t];
            a1 += qv * w1[c * 512 + t + 256];
        }
        x1L[t]       = a0 / (1.f + __expf(-a0));
        x1L[t + 256] = a1 / (1.f + __expf(-a1));
        __syncthreads();
        int d = t & 63, ks = t >> 6;
        float acc = 0.f;
#pragma unroll 4
        for (int k = ks * 128; k < ks * 128 + 128; ++k)
            acc += x1L[k] * w2[k * 512 + e * 64 + d];
        ps[ks][d] = acc;
        __syncthreads();
        if (t < 64)
            qhL[t] = b2[e * 64 + t] + ps[0][t] + ps[1][t] + ps[2][t] + ps[3][t];
        __syncthreads();
        const float* row = w_kv + (size_t)t * 1024 + e * 128;   // K-half of head e
        float a2 = 0.f;
#pragma unroll
        for (int dd = 0; dd < 64; dd += 4) {
            float4 wv4 = *(const float4*)(row + dd);
            a2 += qhL[dd] * wv4.x + qhL[dd + 1] * wv4.y + qhL[dd + 2] * wv4.z + qhL[dd + 3] * wv4.w;
        }
        qkw[(b * 8 + e) * 256 + t] = (f16)(a2 * rms_w[t]);
    } else {
        // ---- M role: (e, 8-c tile) ----
        int mb = blk - 64;
        int e = mb >> 5, c0 = (mb & 31) * 8;
        {
            int d = t & 63, cc = t >> 6;
            wv[d][cc]     = w_kv[(size_t)(c0 + cc) * 1024 + e * 128 + 64 + d];
            wv[d][cc + 4] = w_kv[(size_t)(c0 + cc + 4) * 1024 + e * 128 + 64 + d];
        }
        __syncthreads();
        int o = t;
        float acc[8];
#pragma unroll
        for (int c = 0; c < 8; ++c) acc[c] = 0.f;
#pragma unroll 4
        for (int d = 0; d < 64; ++d) {
            float wo = w_out[(size_t)(e * 64 + d) * 256 + o];
            float4 wa = *(const float4*)&wv[d][0];
            float4 wb = *(const float4*)&wv[d][4];
            acc[0] += wa.x * wo; acc[1] += wa.y * wo; acc[2] += wa.z * wo; acc[3] += wa.w * wo;
            acc[4] += wb.x * wo; acc[5] += wb.y * wo; acc[6] += wb.z * wo; acc[7] += wb.w * wo;
        }
        f16x8 ov;
#pragma unroll
        for (int c = 0; c < 8; ++c) ov[c] = (f16)(acc[c] * rms_w[c0 + c]);
        *(f16x8*)(mtp + ((size_t)((e * 256 + c0) >> 3) * 256 + o) * 8) = ov;
    }
}

// ---------------------------------------------------------------------------
// k_attn: 512 threads, 16 pixels/block, grid 512 (tile*8 + b).
// phases: [load g-pairs, deep MLP] -> [dots MFMA] -> [softmax+blend fused,
// pk-f16, B-frag preload in flight] -> [GEMM vs mtp] -> store.  3 barriers.
// ---------------------------------------------------------------------------
__launch_bounds__(512, 4)
__global__ void k_attn(const float* __restrict__ cin, const f16* __restrict__ qkw,
                       const f16* __restrict__ mtp, const float* __restrict__ b_out,
                       float* __restrict__ out) {
    int blk = blockIdx.x;
    int b = blk & 7;
    int hw0 = (blk >> 3) * 16;
    int t = threadIdx.x;
    int lane = t & 63, w = t >> 6;        // w 0..7
    int m16 = lane & 15, quad = lane >> 4;

    __shared__ char A[16 * 4096];         // 65536 B, swizzled f16 [16px][2048k]
    __shared__ float dotsP[8][8][16];     //  4096 B [n][e][px]
    __shared__ float wred[8][8][16];      //  4096 B [w][n][px]

    // ---- load raw c -> A (f16, swizzled): thread = (px, 8-ch block) ----
    int px = t & 15, cb = t >> 4;         // cb 0..31
    const float* cbase = cin + ((size_t)b * 8 * 256) * 1024 + hw0 + px;
#pragma unroll
    for (int g = 0; g < 8; g += 2) {      // g-pair: 16 loads in flight
        const float* s0 = cbase + ((size_t)(g * 256 + cb * 8) << 10);
        const float* s1 = cbase + ((size_t)((g + 1) * 256 + cb * 8) << 10);
        float v0[8], v1[8];
#pragma unroll
        for (int j = 0; j < 8; ++j) v0[j] = s0[(size_t)j << 10];
#pragma unroll
        for (int j = 0; j < 8; ++j) v1[j] = s1[(size_t)j << 10];
        float sa = 0.f, sb = 0.f;
        f16x8 h0, h1;
#pragma unroll
        for (int j = 0; j < 8; ++j) { sa += v0[j] * v0[j]; h0[j] = (f16)v0[j]; }
#pragma unroll
        for (int j = 0; j < 8; ++j) { sb += v1[j] * v1[j]; h1[j] = (f16)v1[j]; }
        *(f16x8*)a_addr(A, px, g * 256 + cb * 8)       = h0;
        *(f16x8*)a_addr(A, px, (g + 1) * 256 + cb * 8) = h1;
        sa += __shfl_xor(sa, 16); sa += __shfl_xor(sa, 32);
        sb += __shfl_xor(sb, 16); sb += __shfl_xor(sb, 32);
        if (lane < 16) {
            wred[w][g][px]     = sa;
            wred[w][g + 1][px] = sb;
        }
    }
    __syncthreads();

    // ---- dots via MFMA (wave w -> n=w) ----
    {
        f32x4 d0 = {0.f, 0.f, 0.f, 0.f};
        const f16* qrow = qkw + (size_t)b * 2048 + (m16 & 7) * 256;
#pragma unroll
        for (int ks = 0; ks < 8; ++ks) {
            f16x8 a0  = *(const f16x8*)a_addr(A, m16, w * 256 + ks * 32 + quad * 8);
            f16x8 bfr = *(const f16x8*)(qrow + ks * 32 + quad * 8);
            d0 = __builtin_amdgcn_mfma_f32_16x16x32_f16(a0, bfr, d0, 0, 0, 0);
        }
        if (m16 < 8) {   // D: col=m16=e, row=quad*4+r=p
#pragma unroll
            for (int r = 0; r < 4; ++r) dotsP[w][m16][quad * 4 + r] = d0[r];
        }
    }
    __syncthreads();

    // ---- GEMM B-frag preload (ks 0..3), in flight across blend ----
    f16x8 pb[4][2];
#pragma unroll
    for (int ks = 0; ks < 4; ++ks) {
        int kchunk = ks * 4 + quad;
#pragma unroll
        for (int ot = 0; ot < 2; ++ot)
            pb[ks][ot] = *(const f16x8*)(mtp + ((size_t)kchunk * 256
                                         + w * 32 + ot * 16 + m16) * 8);
    }

    // ---- fused softmax + blend (in place over A), pk-f16 math ----
    {
        int bpx = t & 15, c0 = (t >> 4) * 8;   // 16 px x 32 c-windows of 8
        float rinv[8];
#pragma unroll
        for (int n = 0; n < 8; ++n) {
            float ss = 0.f;
#pragma unroll
            for (int ww = 0; ww < 8; ++ww) ss += wred[ww][n][bpx];
            rinv[n] = rsqrtf(ss * (1.f / 256.f) + 1e-6f);
        }
        f16x8 cv[8];
#pragma unroll
        for (int n = 0; n < 8; ++n)
            cv[n] = *(const f16x8*)a_addr(A, bpx, n * 256 + c0);
#pragma unroll
        for (int e = 0; e < 8; ++e) {
            float l[8];
#pragma unroll
            for (int n = 0; n < 8; ++n) l[n] = dotsP[n][e][bpx] * rinv[n] * 0.125f;
            float mx = l[0];
#pragma unroll
            for (int n = 1; n < 8; ++n) mx = fmaxf(mx, l[n]);
            float s = 0.f;
#pragma unroll
            for (int n = 0; n < 8; ++n) { l[n] = __expf(l[n] - mx); s += l[n]; }
            float inv = 1.f / s;
            f16x8 r = {};
#pragma unroll
            for (int n = 0; n < 8; ++n) {
                f16 an = (f16)(l[n] * inv * rinv[n]);
#pragma unroll
                for (int j = 0; j < 8; ++j) r[j] += cv[n][j] * an;   // v_pk_fma_f16
            }
            *(f16x8*)a_addr(A, bpx, e * 256 + c0) = r;
        }
    }
    __syncthreads();

    // ---- GEMM: out[16p][256o] = A[16][2048] @ M  (wave w -> o 32-slice) ----
    {
        f32x4 acc[2];
        acc[0] = (f32x4){0.f, 0.f, 0.f, 0.f};
        acc[1] = (f32x4){0.f, 0.f, 0.f, 0.f};
#pragma unroll
        for (int ks = 0; ks < 4; ++ks) {   // preloaded B
            f16x8 af = *(const f16x8*)a_addr(A, m16, ks * 32 + quad * 8);
            acc[0] = __builtin_amdgcn_mfma_f32_16x16x32_f16(af, pb[ks][0], acc[0], 0, 0, 0);
            acc[1] = __builtin_amdgcn_mfma_f32_16x16x32_f16(af, pb[ks][1], acc[1], 0, 0, 0);
        }
#pragma unroll 8
        for (int ks = 4; ks < 64; ++ks) {
            int k = (ks >> 3) * 256 + (ks & 7) * 32 + quad * 8;
            f16x8 af = *(const f16x8*)a_addr(A, m16, k);
            int kchunk = k >> 3;
#pragma unroll
            for (int ot = 0; ot < 2; ++ot) {
                f16x8 bfr = *(const f16x8*)(mtp + ((size_t)kchunk * 256
                                            + w * 32 + ot * 16 + m16) * 8);
                acc[ot] = __builtin_amdgcn_mfma_f32_16x16x32_f16(af, bfr, acc[ot], 0, 0, 0);
            }
        }
#pragma unroll
        for (int ot = 0; ot < 2; ++ot) {
            int o = w * 32 + ot * 16 + m16;
            float bo = b_out[o];
            float4 vv = {acc[ot][0] + bo, acc[ot][1] + bo, acc[ot][2] + bo, acc[ot][3] + bo};
            *(float4*)(out + ((size_t)b * 256 + o) * 1024 + hw0 + quad * 4) = vv;
        }
    }
}

extern "C" void kernel_launch(void* const* d_in, const int* in_sizes, int n_in,
                              void* d_out, int out_size, void* d_ws, size_t ws_size,
                              hipStream_t stream) {
    (void)in_sizes; (void)n_in; (void)out_size; (void)ws_size;
    const int*   q     = (const int*)d_in[0];
    const float* c     = (const float*)d_in[1];
    const float* rms_w = (const float*)d_in[2];
    const float* emb   = (const float*)d_in[3];
    const float* w1    = (const float*)d_in[4];
    const float* b1    = (const float*)d_in[5];
    const float* w2    = (const float*)d_in[6];
    const float* b2    = (const float*)d_in[7];
    const float* w_kv  = (const float*)d_in[8];
    const float* w_out = (const float*)d_in[9];
    const float* b_out = (const float*)d_in[10];
    float* out = (float*)d_out;

    // ws layout: qkw [8b][8e][256c] f16 = 32 KiB at 0; mtp [256kc][256o][8] f16 = 1 MiB
    char* ws = (char*)d_ws;
    f16* qkw = (f16*)ws;                 // [0, 32768)
    f16* mtp = (f16*)(ws + 32768);       // [32768, +1 MiB)

    k_setup<<<320, 256, 0, stream>>>(q, emb, w1, b1, w2, b2, w_kv, w_out, rms_w, qkw, mtp);
    k_attn <<<512, 512, 0, stream>>>(c, qkw, mtp, b_out, out);
}

// Round 8
// 167.134 us; speedup vs baseline: 1.2563x; 1.0371x over previous
//
#include <hip/hip_runtime.h>

typedef _Float16 f16;
typedef _Float16 f16x8 __attribute__((ext_vector_type(8)));
typedef float f32x4 __attribute__((ext_vector_type(4)));

// A[px][k]: 32 px rows x 2048 f16 (4096 B per row). 16-B chunks XOR-swizzled
// by px (4 bits): byte = px*4096 + ((k>>3)^(px&15))*16 + (k&7)*2.
// Lane maps below are chosen so every wave's two 32-lane halves target chunk
// groups 16 apart -> all LDS ops <= 2-way (free).
static __device__ inline char* a_addr(char* Abase, int px, int k) {
    return Abase + px * 4096 + ((((k >> 3) ^ (px & 15)) << 4) | ((k & 7) << 1));
}

// ---------------------------------------------------------------------------
// k_setup: one launch, no internal deps.
// blocks 0..63:   (b,e): full query path redundantly
// blocks 64..319: M_e = Wv_e @ w_out_e, rw-folded -> mtp[kchunk][o][8] f16
// ---------------------------------------------------------------------------
__launch_bounds__(256)
__global__ void k_setup(const int* __restrict__ q, const float* __restrict__ emb,
                        const float* __restrict__ w1, const float* __restrict__ b1,
                        const float* __restrict__ w2, const float* __restrict__ b2,
                        const float* __restrict__ w_kv, const float* __restrict__ w_out,
                        const float* __restrict__ rms_w,
                        f16* __restrict__ qkw, f16* __restrict__ mtp) {
    int blk = blockIdx.x;
    int t = threadIdx.x;
    __shared__ float qe[256];
    __shared__ float x1L[512];
    __shared__ float ps[4][64];
    __shared__ float qhL[64];
    __shared__ float wv[64][8];

    if (blk < 64) {
        // ---- query-path role: (b, e) ----
        int b = blk >> 3, e = blk & 7;
        qe[t] = emb[(size_t)q[b] * 256 + t];
        __syncthreads();
        float a0 = b1[t], a1 = b1[t + 256];
#pragma unroll 4
        for (int c = 0; c < 256; ++c) {
            float qv = qe[c];
            a0 += qv * w1[c * 512 + t];
            a1 += qv * w1[c * 512 + t + 256];
        }
        x1L[t]       = a0 / (1.f + __expf(-a0));
        x1L[t + 256] = a1 / (1.f + __expf(-a1));
        __syncthreads();
        int d = t & 63, ks = t >> 6;
        float acc = 0.f;
#pragma unroll 4
        for (int k = ks * 128; k < ks * 128 + 128; ++k)
            acc += x1L[k] * w2[k * 512 + e * 64 + d];
        ps[ks][d] = acc;
        __syncthreads();
        if (t < 64)
            qhL[t] = b2[e * 64 + t] + ps[0][t] + ps[1][t] + ps[2][t] + ps[3][t];
        __syncthreads();
        const float* row = w_kv + (size_t)t * 1024 + e * 128;   // K-half of head e
        float a2 = 0.f;
#pragma unroll
        for (int dd = 0; dd < 64; dd += 4) {
            float4 wv4 = *(const float4*)(row + dd);
            a2 += qhL[dd] * wv4.x + qhL[dd + 1] * wv4.y + qhL[dd + 2] * wv4.z + qhL[dd + 3] * wv4.w;
        }
        qkw[(b * 8 + e) * 256 + t] = (f16)(a2 * rms_w[t]);
    } else {
        // ---- M role: (e, 8-c tile) ----
        int mb = blk - 64;
        int e = mb >> 5, c0 = (mb & 31) * 8;
        {
            int d = t & 63, cc = t >> 6;
            wv[d][cc]     = w_kv[(size_t)(c0 + cc) * 1024 + e * 128 + 64 + d];
            wv[d][cc + 4] = w_kv[(size_t)(c0 + cc + 4) * 1024 + e * 128 + 64 + d];
        }
        __syncthreads();
        int o = t;
        float acc[8];
#pragma unroll
        for (int c = 0; c < 8; ++c) acc[c] = 0.f;
#pragma unroll 4
        for (int d = 0; d < 64; ++d) {
            float wo = w_out[(size_t)(e * 64 + d) * 256 + o];
            float4 wa = *(const float4*)&wv[d][0];
            float4 wb = *(const float4*)&wv[d][4];
            acc[0] += wa.x * wo; acc[1] += wa.y * wo; acc[2] += wa.z * wo; acc[3] += wa.w * wo;
            acc[4] += wb.x * wo; acc[5] += wb.y * wo; acc[6] += wb.z * wo; acc[7] += wb.w * wo;
        }
        f16x8 ov;
#pragma unroll
        for (int c = 0; c < 8; ++c) ov[c] = (f16)(acc[c] * rms_w[c0 + c]);
        *(f16x8*)(mtp + ((size_t)((e * 256 + c0) >> 3) * 256 + o) * 8) = ov;
    }
}

// ---------------------------------------------------------------------------
// k_attn: 1024 threads, 32 pixels/block, grid 256 (tile*8 + b). 1 block/CU.
// phases: [load + sumsq] -> [rinv(t<256) + dots MFMA] -> [fused softmax+blend,
// B preload in flight] -> [GEMM: wave w -> o 16-slice, px halves] -> store.
// ---------------------------------------------------------------------------
__launch_bounds__(1024, 4)
__global__ void k_attn(const float* __restrict__ cin, const f16* __restrict__ qkw,
                       const f16* __restrict__ mtp, const float* __restrict__ b_out,
                       float* __restrict__ out) {
    int blk = blockIdx.x;
    int b = blk & 7;
    int hw0 = (blk >> 3) * 32;
    int t = threadIdx.x;
    int lane = t & 63, w = t >> 6;        // w 0..15
    int m16 = lane & 15, quad = lane >> 4;
    int half = lane >> 5;                 // 0/1

    __shared__ char A[32 * 4096];         // 131072 B, swizzled f16 [32px][2048k]
    __shared__ float dotsP[8][8][32];     //   8192 B [n][e][px]
    __shared__ float wred[16][8][32];     //  16384 B [w][n][px]
    __shared__ float rinvL[32][8];        //   1024 B

    // ---- load raw c -> A (f16, swizzled): thread = (px, 8-ch block cb) ----
    int px = lane & 31;
    int cb = w + half * 16;               // halves 16 apart -> 2-way stores
    const float* cbase = cin + ((size_t)b * 8 * 256) * 1024 + hw0 + px;
#pragma unroll
    for (int g = 0; g < 8; g += 2) {      // g-pair: 16 loads in flight
        const float* s0 = cbase + ((size_t)(g * 256 + cb * 8) << 10);
        const float* s1 = cbase + ((size_t)((g + 1) * 256 + cb * 8) << 10);
        float v0[8], v1[8];
#pragma unroll
        for (int j = 0; j < 8; ++j) v0[j] = s0[(size_t)j << 10];
#pragma unroll
        for (int j = 0; j < 8; ++j) v1[j] = s1[(size_t)j << 10];
        float sa = 0.f, sb = 0.f;
        f16x8 h0, h1;
#pragma unroll
        for (int j = 0; j < 8; ++j) { sa += v0[j] * v0[j]; h0[j] = (f16)v0[j]; }
#pragma unroll
        for (int j = 0; j < 8; ++j) { sb += v1[j] * v1[j]; h1[j] = (f16)v1[j]; }
        *(f16x8*)a_addr(A, px, g * 256 + cb * 8)       = h0;
        *(f16x8*)a_addr(A, px, (g + 1) * 256 + cb * 8) = h1;
        sa += __shfl_xor(sa, 32);         // combine the two cb halves (same px)
        sb += __shfl_xor(sb, 32);
        if (lane < 32) {
            wred[w][g][px]     = sa;
            wred[w][g + 1][px] = sb;
        }
    }
    __syncthreads();

    // ---- rinv (t<256) + dots via MFMA (wave w -> n=w&7, px-half=w>>3) ----
    if (t < 256) {
        int p = t >> 3, n = t & 7;
        float ss = 0.f;
#pragma unroll
        for (int ww = 0; ww < 16; ++ww) ss += wred[ww][n][p];
        rinvL[p][n] = rsqrtf(ss * (1.f / 256.f) + 1e-6f);
    }
    {
        int n = w & 7, pxh = w >> 3;
        f32x4 d0 = {0.f, 0.f, 0.f, 0.f};
        const f16* qrow = qkw + (size_t)b * 2048 + (m16 & 7) * 256;
#pragma unroll
        for (int ks = 0; ks < 8; ++ks) {
            f16x8 a0  = *(const f16x8*)a_addr(A, pxh * 16 + m16, n * 256 + ks * 32 + quad * 8);
            f16x8 bfr = *(const f16x8*)(qrow + ks * 32 + quad * 8);
            d0 = __builtin_amdgcn_mfma_f32_16x16x32_f16(a0, bfr, d0, 0, 0, 0);
        }
        if (m16 < 8) {   // D: col=m16=e, row=quad*4+r
#pragma unroll
            for (int r = 0; r < 4; ++r) dotsP[n][m16][pxh * 16 + quad * 4 + r] = d0[r];
        }
    }
    __syncthreads();

    // ---- GEMM B-frag preload (ks 0..7), in flight across blend ----
    int o = w * 16 + m16;
    f16x8 pb[8];
#pragma unroll
    for (int ks = 0; ks < 8; ++ks)
        pb[ks] = *(const f16x8*)(mtp + ((size_t)(ks * 4 + quad) * 256 + o) * 8);

    // ---- fused softmax + blend (in place over A), pk-f16 math ----
    {
        int bpx = lane & 31;
        int c0 = (w + half * 16) * 8;     // halves 16 windows apart -> 2-way
        float rinv[8];
#pragma unroll
        for (int n = 0; n < 8; ++n) rinv[n] = rinvL[bpx][n];
        f16x8 cv[8];
#pragma unroll
        for (int n = 0; n < 8; ++n)
            cv[n] = *(const f16x8*)a_addr(A, bpx, n * 256 + c0);
#pragma unroll
        for (int e = 0; e < 8; ++e) {
            float l[8];
#pragma unroll
            for (int n = 0; n < 8; ++n) l[n] = dotsP[n][e][bpx] * rinv[n] * 0.125f;
            float mx = l[0];
#pragma unroll
            for (int n = 1; n < 8; ++n) mx = fmaxf(mx, l[n]);
            float s = 0.f;
#pragma unroll
            for (int n = 0; n < 8; ++n) { l[n] = __expf(l[n] - mx); s += l[n]; }
            float inv = 1.f / s;
            f16x8 r = {};
#pragma unroll
            for (int n = 0; n < 8; ++n) {
                f16 an = (f16)(l[n] * inv * rinv[n]);
#pragma unroll
                for (int j = 0; j < 8; ++j) r[j] += cv[n][j] * an;   // v_pk_fma_f16
            }
            *(f16x8*)a_addr(A, bpx, e * 256 + c0) = r;
        }
    }
    __syncthreads();

    // ---- GEMM: out[32p][256o] = A[32][2048] @ M  (wave w -> o 16-slice) ----
    {
        f32x4 acc0 = {0.f, 0.f, 0.f, 0.f};
        f32x4 acc1 = {0.f, 0.f, 0.f, 0.f};
#pragma unroll
        for (int ks = 0; ks < 8; ++ks) {   // preloaded B
            int k = ks * 32 + quad * 8;
            f16x8 af0 = *(const f16x8*)a_addr(A, m16, k);
            f16x8 af1 = *(const f16x8*)a_addr(A, m16 + 16, k);
            acc0 = __builtin_amdgcn_mfma_f32_16x16x32_f16(af0, pb[ks], acc0, 0, 0, 0);
            acc1 = __builtin_amdgcn_mfma_f32_16x16x32_f16(af1, pb[ks], acc1, 0, 0, 0);
        }
#pragma unroll 8
        for (int ks = 8; ks < 64; ++ks) {
            int k = (ks >> 3) * 256 + (ks & 7) * 32 + quad * 8;
            int kchunk = k >> 3;
            f16x8 bfr = *(const f16x8*)(mtp + ((size_t)kchunk * 256 + o) * 8);
            f16x8 af0 = *(const f16x8*)a_addr(A, m16, k);
            f16x8 af1 = *(const f16x8*)a_addr(A, m16 + 16, k);
            acc0 = __builtin_amdgcn_mfma_f32_16x16x32_f16(af0, bfr, acc0, 0, 0, 0);
            acc1 = __builtin_amdgcn_mfma_f32_16x16x32_f16(af1, bfr, acc1, 0, 0, 0);
        }
        float bo = b_out[o];
        float* drow = out + ((size_t)b * 256 + o) * 1024 + hw0;
        float4 v0 = {acc0[0] + bo, acc0[1] + bo, acc0[2] + bo, acc0[3] + bo};
        float4 v1 = {acc1[0] + bo, acc1[1] + bo, acc1[2] + bo, acc1[3] + bo};
        *(float4*)(drow + quad * 4)      = v0;   // px 0..15 half
        *(float4*)(drow + 16 + quad * 4) = v1;   // px 16..31 half
    }
}

extern "C" void kernel_launch(void* const* d_in, const int* in_sizes, int n_in,
                              void* d_out, int out_size, void* d_ws, size_t ws_size,
                              hipStream_t stream) {
    (void)in_sizes; (void)n_in; (void)out_size; (void)ws_size;
    const int*   q     = (const int*)d_in[0];
    const float* c     = (const float*)d_in[1];
    const float* rms_w = (const float*)d_in[2];
    const float* emb   = (const float*)d_in[3];
    const float* w1    = (const float*)d_in[4];
    const float* b1    = (const float*)d_in[5];
    const float* w2    = (const float*)d_in[6];
    const float* b2    = (const float*)d_in[7];
    const float* w_kv  = (const float*)d_in[8];
    const float* w_out = (const float*)d_in[9];
    const float* b_out = (const float*)d_in[10];
    float* out = (float*)d_out;

    // ws layout: qkw [8b][8e][256c] f16 = 32 KiB at 0; mtp [256kc][256o][8] f16 = 1 MiB
    char* ws = (char*)d_ws;
    f16* qkw = (f16*)ws;                 // [0, 32768)
    f16* mtp = (f16*)(ws + 32768);       // [32768, +1 MiB)

    k_setup<<<320, 256, 0, stream>>>(q, emb, w1, b1, w2, b2, w_kv, w_out, rms_w, qkw, mtp);
    k_attn <<<256, 1024, 0, stream>>>(c, qkw, mtp, b_out, out);
}